// Round 1
// baseline (474.878 us; speedup 1.0000x reference)
//
#include <hip/hip_runtime.h>
#include <cstdint>

#define NH 16
#define HD 128
#define BS 16
#define NTBL 96
#define PT_OFF 32           // prompt blocks skipped: 512/16
#define NSPLIT 4
#define BLOCKS_PER_SPLIT 16 // 256 positions per split
#define QK_SCALE 0.08838834764831845f
#define NEG_INF -1e30f
#define NB 16               // batch

// Scatter k_new/v_new into the paged caches at slot = ctx-1 (reference's .at[].set()).
__global__ __launch_bounds__(128) void cache_update_kernel(
    const float* __restrict__ k_new, const float* __restrict__ v_new,
    const int* __restrict__ slot_mapping,
    float* __restrict__ key_cache, float* __restrict__ value_cache)
{
    const int h = blockIdx.x, b = blockIdx.y, d = threadIdx.x;
    const int slot = slot_mapping[b];           // (B,1) -> col 0
    const int bi = slot >> 4, off = slot & 15;
    const float kv = k_new[(size_t)b*2048 + h*HD + d];
    const float vv = v_new[(size_t)b*2048 + h*HD + d];
    key_cache  [(((size_t)bi*NH + h)*BS + off)*HD + d] = kv;   // [blk][h][row][d]
    value_cache[(((size_t)bi*NH + h)*HD + d)*BS + off] = vv;   // [blk][h][d][row]
}

// Flash-decoding split: each WG handles 16 KV blocks (256 positions) for one (b,h).
// Writes partial O[128], m, l to workspace.
__global__ __launch_bounds__(256) void attn_split_kernel(
    const float* __restrict__ q,
    const float* __restrict__ key_cache,
    const float* __restrict__ value_cache,
    const int* __restrict__ block_tables,
    const int* __restrict__ context_lens,
    const float* __restrict__ attn_bias,
    float* __restrict__ ws)
{
    const int s = blockIdx.x, h = blockIdx.y, b = blockIdx.z;
    const int ctx = context_lens[b];
    const int nb_ctx = (ctx + BS - 1) >> 4;      // blocks with any valid position
    const int jl0 = s * BLOCKS_PER_SPLIT;
    if (jl0 >= nb_ctx) return;                   // inactive split (uniform per WG)
    const int nbl = min(BLOCKS_PER_SPLIT, nb_ctx - jl0);

    __shared__ float sc[256];     // scores -> probs for this split
    __shared__ float red[8];
    __shared__ float outred[128];

    const int tid = threadIdx.x;
    const int wave = tid >> 6, lane = tid & 63;
    const int half = lane >> 5, lq = lane & 31;

    // Per-lane query fragment: dims [lq*4, lq*4+4) (both 32-lane halves load same 128B)
    const float4 qv = *(const float4*)(q + (size_t)b*2048 + h*HD + lq*4);
    const int* bt = block_tables + b*NTBL + PT_OFF + jl0;
    const float* bias = attn_bias + ((size_t)b*NH + h)*1024 + jl0*BS;

    // ---- QK: each wave streams whole 8KB key blocks with coalesced float4s.
    // slot = i*64+lane covers position slot/32, dims (slot%32)*4.
    for (int jl = wave; jl < nbl; jl += 4) {
        const int blk = bt[jl];
        const float4* kb = (const float4*)(key_cache + ((size_t)blk*NH + h)*2048);
        #pragma unroll
        for (int i = 0; i < 8; ++i) {
            const float4 kv = kb[i*64 + lane];
            float part = kv.x*qv.x + kv.y*qv.y + kv.z*qv.z + kv.w*qv.w;
            part += __shfl_xor(part, 1);
            part += __shfl_xor(part, 2);
            part += __shfl_xor(part, 4);
            part += __shfl_xor(part, 8);
            part += __shfl_xor(part, 16);   // 32-lane half now holds full 128-dim dot
            if (lq == 0) {
                const int r = i*2 + half;          // row within block
                const int t = jl*16 + r;           // local position in split
                const bool valid = (jl0*16 + t) < ctx;
                sc[t] = valid ? (part*QK_SCALE + bias[t]) : NEG_INF;
            }
        }
    }
    __syncthreads();

    // ---- partial softmax over this split's positions
    const int n_spos = nbl * 16;
    const float x = (tid < n_spos) ? sc[tid] : NEG_INF;
    float m = x;
    #pragma unroll
    for (int msk = 32; msk >= 1; msk >>= 1) m = fmaxf(m, __shfl_xor(m, msk));
    if (lane == 0) red[wave] = m;
    __syncthreads();
    m = fmaxf(fmaxf(red[0], red[1]), fmaxf(red[2], red[3]));

    const float pexp = (tid < n_spos) ? __expf(x - m) : 0.0f;   // masked -> exp(-1e30)=0
    float l = pexp;
    #pragma unroll
    for (int msk = 32; msk >= 1; msk >>= 1) l += __shfl_xor(l, msk);
    if (lane == 0) red[4 + wave] = l;
    if (tid < n_spos) sc[tid] = pexp;   // own slot only; no cross-read before next sync
    __syncthreads();
    l = red[4] + red[5] + red[6] + red[7];

    // ---- PV: thread owns dim d; reads the 64B d-row of each value block (4x float4).
    // Two teams split blocks to use all 256 threads.
    const int team = tid >> 7, d = tid & 127;
    float acc = 0.0f;
    for (int jl = team; jl < nbl; jl += 2) {
        const int blk = bt[jl];
        const float4* vb = (const float4*)(value_cache + ((size_t)blk*NH + h)*2048 + d*16);
        const float4 v0 = vb[0], v1 = vb[1], v2 = vb[2], v3 = vb[3];
        const float* pr = sc + jl*16;    // LDS broadcast (uniform addr per wave)
        acc += pr[0]*v0.x + pr[1]*v0.y + pr[2]*v0.z  + pr[3]*v0.w;
        acc += pr[4]*v1.x + pr[5]*v1.y + pr[6]*v1.z  + pr[7]*v1.w;
        acc += pr[8]*v2.x + pr[9]*v2.y + pr[10]*v2.z + pr[11]*v2.w;
        acc += pr[12]*v3.x + pr[13]*v3.y + pr[14]*v3.z + pr[15]*v3.w;
    }
    if (team == 0) outred[d] = acc;
    __syncthreads();
    if (team == 1) outred[d] += acc;
    __syncthreads();

    float* wsp = ws + (((size_t)b*NH + h)*NSPLIT + s)*130;
    if (tid < 128) wsp[tid] = outred[tid];
    if (tid == 0) { wsp[128] = m; wsp[129] = l; }
}

// Combine up to NSPLIT partials per (b,h): online-softmax merge.
__global__ __launch_bounds__(128) void reduce_kernel(
    const float* __restrict__ ws, const int* __restrict__ context_lens,
    float* __restrict__ out)
{
    const int h = blockIdx.x, b = blockIdx.y, d = threadIdx.x;
    const int ctx = context_lens[b];
    const int nsv = (ctx + 255) >> 8;       // active splits (>=1)
    const float* base = ws + ((size_t)b*NH + h)*NSPLIT*130;
    float M = NEG_INF;
    for (int s2 = 0; s2 < nsv; ++s2) M = fmaxf(M, base[s2*130 + 128]);
    float L = 0.0f, acc = 0.0f;
    for (int s2 = 0; s2 < nsv; ++s2) {
        const float w = __expf(base[s2*130 + 128] - M);
        L   += base[s2*130 + 129] * w;
        acc += base[s2*130 + d] * w;
    }
    out[(size_t)b*2048 + h*HD + d] = acc / L;
}

extern "C" void kernel_launch(void* const* d_in, const int* in_sizes, int n_in,
                              void* d_out, int out_size, void* d_ws, size_t ws_size,
                              hipStream_t stream) {
    (void)in_sizes; (void)n_in; (void)out_size; (void)ws_size;
    const float* q      = (const float*)d_in[0];
    const float* k_new  = (const float*)d_in[1];
    const float* v_new  = (const float*)d_in[2];
    float* key_cache    = (float*)d_in[3];
    float* value_cache  = (float*)d_in[4];
    const int* slot_map = (const int*)d_in[5];
    const int* btables  = (const int*)d_in[6];
    const int* ctx_lens = (const int*)d_in[7];
    const float* bias   = (const float*)d_in[8];
    float* ws = (float*)d_ws;     // needs 16*16*4*130*4 = 532480 B
    float* out = (float*)d_out;

    cache_update_kernel<<<dim3(NH, NB), 128, 0, stream>>>(k_new, v_new, slot_map,
                                                          key_cache, value_cache);
    attn_split_kernel<<<dim3(NSPLIT, NH, NB), 256, 0, stream>>>(q, key_cache, value_cache,
                                                                btables, ctx_lens, bias, ws);
    reduce_kernel<<<dim3(NH, NB), 128, 0, stream>>>(ws, ctx_lens, out);
}

// Round 2
// 451.574 us; speedup vs baseline: 1.0516x; 1.0516x over previous
//
#include <hip/hip_runtime.h>
#include <cstdint>

#define NH 16
#define HD 128
#define BS 16
#define NTBL 96
#define PT_OFF 32            // prompt blocks skipped: 512/16
#define NSPLIT 16
#define SPLIT_BLOCKS 4       // 64 positions per split
#define QK_SCALE 0.08838834764831845f
#define NEG_INF -1e30f
#define NB 16                // batch

// Flash-decoding split over the CACHED positions [0, ctx-1) only.
// The new token (position ctx-1, k_new/v_new) is merged in reduce_kernel,
// so the paged caches are never written (reference's scatter only matters
// through its effect on out).
__global__ __launch_bounds__(256) void attn_split_kernel(
    const float* __restrict__ q,
    const float* __restrict__ key_cache,
    const float* __restrict__ value_cache,
    const int* __restrict__ block_tables,
    const int* __restrict__ context_lens,
    const float* __restrict__ attn_bias,
    float* __restrict__ ws)
{
    const int s = blockIdx.x, h = blockIdx.y, b = blockIdx.z;
    const int ctx = context_lens[b];
    const int cap = ctx - 1;                 // cached positions: [0, cap)
    const int nbc = (ctx + 14) >> 4;         // ceil(cap/16) blocks
    const int jb0 = s * SPLIT_BLOCKS;
    if (jb0 >= nbc) return;                  // inactive split (uniform per WG)
    const int nbl = min(SPLIT_BLOCKS, nbc - jb0);

    __shared__ float sc[64];                 // raw dots
    __shared__ float sp[64];                 // probs (separate array: no RW hazard)
    __shared__ int   sbt[SPLIT_BLOCKS];
    __shared__ float outA[128], outB[128];

    const int tid = threadIdx.x;
    const int wave = tid >> 6, lane = tid & 63;
    const int half = lane >> 5, lq = lane & 31;

    if (tid < SPLIT_BLOCKS) sbt[tid] = block_tables[b*NTBL + PT_OFF + jb0 + tid];

    // Per-lane query fragment: dims [lq*4, lq*4+4)
    const float4 qv = *(const float4*)(q + (size_t)b*2048 + h*HD + lq*4);
    __syncthreads();

    // ---- QK: one wave streams one 8KB key block with coalesced float4s.
    if (wave < nbl) {
        const int blk = sbt[wave];
        const float4* kb = (const float4*)(key_cache + ((size_t)blk*NH + h)*2048);
        #pragma unroll
        for (int i = 0; i < 8; ++i) {
            const float4 kv = kb[i*64 + lane];
            float part = kv.x*qv.x + kv.y*qv.y + kv.z*qv.z + kv.w*qv.w;
            part += __shfl_xor(part, 1);
            part += __shfl_xor(part, 2);
            part += __shfl_xor(part, 4);
            part += __shfl_xor(part, 8);
            part += __shfl_xor(part, 16);   // 32-lane half holds full 128-dim dot
            if (lq == 0) sc[wave*16 + i*2 + half] = part;
        }
    }
    __syncthreads();

    // ---- softmax over <=64 positions, computed redundantly per wave (lane==pos)
    const int pos = lane;
    const int gpos = jb0*16 + pos;
    const bool valid = gpos < cap;           // also masks pos >= nbl*16
    const float x = valid
        ? (sc[pos]*QK_SCALE + attn_bias[((size_t)b*NH + h)*1024 + gpos])
        : NEG_INF;
    float m = x;
    #pragma unroll
    for (int msk = 32; msk >= 1; msk >>= 1) m = fmaxf(m, __shfl_xor(m, msk));
    const float pexp = valid ? __expf(x - m) : 0.0f;
    float l = pexp;
    #pragma unroll
    for (int msk = 32; msk >= 1; msk >>= 1) l += __shfl_xor(l, msk);
    if (wave == 0) sp[lane] = pexp;
    __syncthreads();

    // ---- PV: thread owns dim d; 2 teams split blocks; 64B d-rows as 4x float4
    const int team = tid >> 7, d = tid & 127;
    float acc = 0.0f;
    for (int jl = team; jl < nbl; jl += 2) {
        const int blk = sbt[jl];
        const float4* vb = (const float4*)(value_cache + ((size_t)blk*NH + h)*2048 + d*16);
        const float4 v0 = vb[0], v1 = vb[1], v2 = vb[2], v3 = vb[3];
        const float* pr = sp + jl*16;        // wave-uniform LDS broadcast
        acc += pr[0]*v0.x + pr[1]*v0.y + pr[2]*v0.z  + pr[3]*v0.w;
        acc += pr[4]*v1.x + pr[5]*v1.y + pr[6]*v1.z  + pr[7]*v1.w;
        acc += pr[8]*v2.x + pr[9]*v2.y + pr[10]*v2.z + pr[11]*v2.w;
        acc += pr[12]*v3.x + pr[13]*v3.y + pr[14]*v3.z + pr[15]*v3.w;
    }
    if (team == 0) outA[d] = acc; else outB[d] = acc;
    __syncthreads();

    float* wsp = ws + (((size_t)b*NH + h)*NSPLIT + s)*130;
    if (tid < 128) wsp[tid] = outA[tid] + outB[tid];
    if (tid == 0) { wsp[128] = m; wsp[129] = l; }
}

// Merge split partials + the new token (k_new/v_new at position ctx-1).
__global__ __launch_bounds__(128) void reduce_kernel(
    const float* __restrict__ ws,
    const float* __restrict__ q,
    const float* __restrict__ k_new,
    const float* __restrict__ v_new,
    const int* __restrict__ context_lens,
    const float* __restrict__ attn_bias,
    float* __restrict__ out)
{
    const int h = blockIdx.x, b = blockIdx.y, d = threadIdx.x;
    const int wave = d >> 6, lane = d & 63;
    const int ctx = context_lens[b];
    const int cap = ctx - 1;
    const int nbc = (ctx + 14) >> 4;
    const int nsv = (nbc + SPLIT_BLOCKS - 1) >> 2;   // active splits (may be 0)

    const size_t qoff = (size_t)b*2048 + h*HD + d;
    const float qd = q[qoff], kd = k_new[qoff], vd = v_new[qoff];

    float p = qd * kd;
    #pragma unroll
    for (int msk = 32; msk >= 1; msk >>= 1) p += __shfl_xor(p, msk);
    __shared__ float s2[2];
    if (lane == 0) s2[wave] = p;
    __syncthreads();
    const float score_new = (s2[0] + s2[1]) * QK_SCALE
                          + attn_bias[((size_t)b*NH + h)*1024 + cap];

    const float* base = ws + ((size_t)b*NH + h)*NSPLIT*130;
    float M = score_new;
    for (int s = 0; s < nsv; ++s) M = fmaxf(M, base[s*130 + 128]);
    const float w = __expf(score_new - M);
    float L = w, acc = w * vd;
    for (int s = 0; s < nsv; ++s) {
        const float e = __expf(base[s*130 + 128] - M);
        L   += base[s*130 + 129] * e;
        acc += base[s*130 + d] * e;
    }
    out[qoff] = acc / L;
}

extern "C" void kernel_launch(void* const* d_in, const int* in_sizes, int n_in,
                              void* d_out, int out_size, void* d_ws, size_t ws_size,
                              hipStream_t stream) {
    (void)in_sizes; (void)n_in; (void)out_size; (void)ws_size;
    const float* q        = (const float*)d_in[0];
    const float* k_new    = (const float*)d_in[1];
    const float* v_new    = (const float*)d_in[2];
    const float* kcache   = (const float*)d_in[3];
    const float* vcache   = (const float*)d_in[4];
    const int* btables    = (const int*)d_in[6];
    const int* ctx_lens   = (const int*)d_in[7];
    const float* bias     = (const float*)d_in[8];
    float* ws  = (float*)d_ws;   // needs 16*16*16*130*4 = 532480 B
    float* out = (float*)d_out;

    attn_split_kernel<<<dim3(NSPLIT, NH, NB), 256, 0, stream>>>(
        q, kcache, vcache, btables, ctx_lens, bias, ws);
    reduce_kernel<<<dim3(NH, NB), 128, 0, stream>>>(
        ws, q, k_new, v_new, ctx_lens, bias, out);
}